// Round 4
// baseline (1734.673 us; speedup 1.0000x reference)
//
#include <hip/hip_runtime.h>

namespace {
constexpr int kNDrug = 50000;
constexpr int kNDis  = 50000;
constexpr int kE     = 800000;
constexpr int kR     = 2;
constexpr int kIn    = 2048;   // IN_UNITS
constexpr int kMsg   = 32;     // AGG_UNITS / 3
constexpr int kAgg   = 96;     // AGG_UNITS
constexpr int kOut   = 64;     // OUT_UNITS
constexpr int kBasis = 4;
constexpr float kSlope = 0.1f; // LeakyReLU slope
constexpr int kNTot  = kNDis + kNDrug;            // [0,kNDis)=dis nodes, rest drug nodes
constexpr int kBN    = 66;                        // nodes per bucket -> 1516 buckets = 5.92/CU,
                                                  // 6-resident => near-perfect CU balance (1.01x)
constexpr int kNBuck = (kNTot + kBN - 1) / kBN;   // 1516
constexpr int kSegCap = 2288;                     // entries/bucket (mean 2112, +3.8sigma), 16-mult
constexpr int kFifoCap = 20;                      // bin_pass LDS FIFO depth
constexpr int kFlushThr = 16;                     // flush unit = 16 entries = 64B
constexpr int kBinBlocks = 64;
constexpr int kOvfCap = 4096;
}

// ---------------- one-shot init: W = att@basis, wT = w_fc^T, cursors ----------------
__global__ __launch_bounds__(256) void setup_all(const float* __restrict__ att,
                                                 const float* __restrict__ basis,
                                                 const float* __restrict__ w_fc,
                                                 float* __restrict__ W,
                                                 float* __restrict__ wT,
                                                 int* __restrict__ bcur,
                                                 int* __restrict__ ovfCnt) {
    constexpr int per_r = kIn * kMsg;
    const int blk = blockIdx.x;
    const int t = threadIdx.x;
    if (blk < 512) {                       // W: 2*2048*32 = 131072 elems
        int idx = blk * 256 + t;
        int r = idx / per_r;
        int ic = idx - r * per_r;
        float acc = 0.f;
#pragma unroll
        for (int b = 0; b < kBasis; ++b)
            acc += att[r * kBasis + b] * basis[b * per_r + ic];
        W[idx] = acc;
    } else if (blk == 512) {               // wT[col][k] = w_fc[k][col]
        for (int i = t; i < kOut * kAgg; i += 256) {
            int col = i / kAgg, k = i - col * kAgg;
            wT[i] = w_fc[k * kOut + col];
        }
    } else {                               // blocks 513..518: bcur; 513/t0: ovfCnt
        int i = (blk - 513) * 256 + t;
        if (i < kNBuck) bcur[i] = i * kSegCap;
        if (blk == 513 && t == 0) *ovfCnt = 0;
    }
}

// ---------------- LDS-FIFO binning (64 blocks x 1024 threads) ----------------
// Per-bucket LDS FIFOs flush in 16-entry (64B) aligned units, one global atomic
// per flush. Transient FIFO overshoot spills single entries straight into the
// segment (rare, ~1e3 total); segment-full goes to the ovf list.
// entry = gnode (16b) | rating (bit16) | node-rel-in-bucket (bits 17..23)
__global__ __launch_bounds__(1024) void bin_pass(const int* __restrict__ esrc,
                                                 const int* __restrict__ edst,
                                                 int* __restrict__ bcur,
                                                 unsigned* __restrict__ bin,
                                                 int* __restrict__ ovfCnt,
                                                 unsigned* __restrict__ ovfE,
                                                 int* __restrict__ ovfB) {
    __shared__ unsigned fifo[kNBuck][kFifoCap];  // 121.3 KB
    __shared__ int fcnt[kNBuck];
    __shared__ int flList[kNBuck], flPos[kNBuck];
    __shared__ int nFl;

    const int t = threadIdx.x;
    for (int i = t; i < kNBuck; i += 1024) fcnt[i] = 0;

    const int total = kR * kE;
    const int per = (total + kBinBlocks - 1) / kBinBlocks;   // 25000
    const int e0 = blockIdx.x * per;
    const int e1 = (e0 + per < total) ? e0 + per : total;
    __syncthreads();

    auto place = [&](int node, int gn, int r) {
        int bb = node / kBN;
        int rel = node - bb * kBN;
        unsigned ent = (unsigned)gn | ((unsigned)r << 16) | ((unsigned)rel << 17);
        int pos = atomicAdd(&fcnt[bb], 1);
        if (pos < kFifoCap) {
            fifo[bb][pos] = ent;
        } else {                                   // transient overshoot: direct single-entry spill
            int p = atomicAdd(&bcur[bb], 1);
            if (p < (bb + 1) * kSegCap) bin[p] = ent;
            else { int s = atomicAdd(ovfCnt, 1);
                   if (s < kOvfCap) { ovfE[s] = ent; ovfB[s] = bb; } }
        }
    };

    for (int base = e0; base < e1; base += 2048) {
#pragma unroll
        for (int k = 0; k < 2; ++k) {
            int idx = base + k * 1024 + t;
            if (idx < e1) {
                int r = (idx >= kE) ? 1 : 0;
                int src = esrc[idx], dst = edst[idx];
                place(dst, src, r);            // dis-side entry
                place(kNDis + src, dst, r);    // drug-side entry
            }
        }
        if (t == 0) nFl = 0;
        __syncthreads();
        for (int bb = t; bb < kNBuck; bb += 1024) {
            int c = fcnt[bb]; if (c > kFifoCap) c = kFifoCap;
            if (c >= kFlushThr) {
                int slot = atomicAdd(&nFl, 1);
                flList[slot] = bb;
                flPos[slot] = atomicAdd(&bcur[bb], kFlushThr);
            }
        }
        __syncthreads();
        {   // 64B-unit copies, 16-lane groups
            const int n = nFl, grp = t >> 4, ln = t & 15;
            for (int it = grp; it < n; it += 64) {
                int bb = flList[it], gp = flPos[it];
                unsigned ent = fifo[bb][ln];
                int d = gp + ln;
                if (d < (bb + 1) * kSegCap) bin[d] = ent;
                else { int s = atomicAdd(ovfCnt, 1);
                       if (s < kOvfCap) { ovfE[s] = ent; ovfB[s] = bb; } }
            }
        }
        __syncthreads();
        for (int bb = t; bb < kNBuck; bb += 1024) {
            int c = fcnt[bb]; if (c > kFifoCap) c = kFifoCap;
            if (c >= kFlushThr) {
                for (int j = kFlushThr; j < c; ++j) fifo[bb][j - kFlushThr] = fifo[bb][j];
                fcnt[bb] = c - kFlushThr;
            } else fcnt[bb] = c;
        }
        __syncthreads();
    }

    // final drain of <=kFifoCap tails
    if (t == 0) nFl = 0;
    __syncthreads();
    for (int bb = t; bb < kNBuck; bb += 1024) {
        int c = fcnt[bb]; if (c > kFifoCap) c = kFifoCap;
        fcnt[bb] = c;
        if (c) {
            int slot = atomicAdd(&nFl, 1);
            flList[slot] = bb;
            flPos[slot] = atomicAdd(&bcur[bb], c);
        }
    }
    __syncthreads();
    const int n = nFl, grp = t >> 4, ln = t & 15;
    for (int it = grp; it < n; it += 64) {
        int bb = flList[it], gp = flPos[it], c = fcnt[bb];
        for (int j = ln; j < c; j += 16) {
            unsigned ent = fifo[bb][j];
            int d = gp + j;
            if (d < (bb + 1) * kSegCap) bin[d] = ent;
            else { int s = atomicAdd(ovfCnt, 1);
                   if (s < kOvfCap) { ovfE[s] = ent; ovfB[s] = bb; } }
        }
    }
}

// ---------------- re-insert overflow entries where room remains ----------------
__global__ __launch_bounds__(256) void ovf_drain(int* __restrict__ bcur,
                                                 unsigned* __restrict__ bin,
                                                 const int* __restrict__ ovfCnt,
                                                 const unsigned* __restrict__ ovfE,
                                                 int* __restrict__ ovfB) {
    int n = *ovfCnt; if (n > kOvfCap) n = kOvfCap;
    int i = blockIdx.x * 256 + threadIdx.x;
    if (i >= n) return;
    int bb = ovfB[i];
    int pos = atomicAdd(&bcur[bb], 1);
    if (pos < (bb + 1) * kSegCap) { bin[pos] = ovfE[i]; ovfB[i] = -1; }
}

// ---------------- fused gather: entry-parallel ds_add into LDS h-tile + FC ----------------
// One 256-thread block per 66-node bucket; LDS = h[66][96] only (25.3 KB ->
// 6 blocks/CU, 24 waves/CU, all 1516 blocks resident). Stream phase: each
// half-wave takes one entry per iteration (no loop-carried dependency ->
// compiler pipelines), 3 W-row loads + 3 ds_add_f32. Then ci/LeakyReLU baked
// into h in place, then FC from h (broadcast float4) x wT (L1-hot float4).
__global__ __launch_bounds__(256, 6) void gather_fused(
        const unsigned* __restrict__ bin,
        const int* __restrict__ bcur,
        const int* __restrict__ ovfCnt,
        const unsigned* __restrict__ ovfE,
        const int* __restrict__ ovfB,
        const float* __restrict__ W,
        const float* __restrict__ wT,
        const int* __restrict__ drug_idx, const int* __restrict__ dis_idx,
        const float* __restrict__ cj_drug, const float* __restrict__ cj_dis,
        const float* __restrict__ ci_drug, const float* __restrict__ ci_dis,
        const float* __restrict__ b_fc,
        float* __restrict__ out) {
    __shared__ float h[kBN][kAgg];   // 25,344 B
    float* hflat = &h[0][0];

    const int t = threadIdx.x;
    const int b = blockIdx.x;
    const int bBase = b * kBN;
    for (int i = t; i < kBN * kAgg; i += 256) hflat[i] = 0.f;

    int sOvf = ovfCnt[0]; if (sOvf > kOvfCap) sOvf = kOvfCap;
    const int sb = b * kSegCap;
    __syncthreads();
    int seg = bcur[b] - sb;
    if (seg > kSegCap) seg = kSegCap;

    const int wid  = t >> 6;
    const int lane = t & 63;
    const int half = lane >> 5;
    const int fl   = lane & 31;

    auto feed = [&](unsigned e) {
        const int gn  = (int)(e & 0xffffu);
        const int rel = (int)(e >> 17);
        const bool isDis = (bBase + rel) < kNDis;   // side of the TARGET node
        const int* fidxp = isDis ? drug_idx : dis_idx;
        const float* cjp = isDis ? cj_drug : cj_dis;
        const int b3 = gn * 3;
        const int i0 = fidxp[b3], i1 = fidxp[b3 + 1], i2 = fidxp[b3 + 2];
        const float c = cjp[gn];
        const float* Wr = W + (((e >> 16) & 1u) * (unsigned)(kIn * kMsg));
        atomicAdd(&h[rel][fl],          Wr[(i0 << 5) + fl] * c);
        atomicAdd(&h[rel][kMsg + fl],   Wr[(i1 << 5) + fl] * c);
        atomicAdd(&h[rel][2*kMsg + fl], Wr[(i2 << 5) + fl] * c);
    };

#pragma unroll 4
    for (int s = (wid << 1) + half; s < seg; s += 8)
        feed(bin[sb + s]);

    if (sOvf > 0) {   // rare leftover overflow entries
        for (int s = (wid << 1) + half; s < sOvf; s += 8)
            if (ovfB[s] == b) feed(ovfE[s]);
    }
    __syncthreads();

    // bake ci * LeakyReLU into h in place
    for (int idx = t; idx < kBN * kAgg; idx += 256) {
        int nl = idx / kAgg;
        int g = bBase + nl;
        if (g >= kNTot) break;
        float civ = (g < kNDis) ? ci_dis[g] : ci_drug[g - kNDis];
        float v = hflat[idx] * civ;
        hflat[idx] = (v >= 0.f) ? v : kSlope * v;
    }
    __syncthreads();

    // FC: out[node, lane] = b[lane] + sum_k h[node][k] * wT[lane][k]
    const float4* wtp = (const float4*)(wT + lane * kAgg);
    const float bias = b_fc[lane];
    for (int nl = wid; nl < kBN; nl += 4) {
        int g = bBase + nl;
        if (g >= kNTot) break;   // only last bucket
        size_t orow = (g < kNDis) ? (size_t)(kNDrug + g) : (size_t)(g - kNDis);
        const float4* hv = (const float4*)(&h[nl][0]);
        float acc = bias;
#pragma unroll 8
        for (int q = 0; q < kAgg / 4; ++q) {
            float4 hq = hv[q];
            float4 wq = wtp[q];
            acc = fmaf(hq.x, wq.x, acc);
            acc = fmaf(hq.y, wq.y, acc);
            acc = fmaf(hq.z, wq.z, acc);
            acc = fmaf(hq.w, wq.w, acc);
        }
        out[orow * kOut + lane] = acc;
    }
}

// ---------------- fallback path (R1 atomic scatter, tiny-ws only) ----------------
__global__ __launch_bounds__(256) void build_W_fb(const float* __restrict__ att,
                                                  const float* __restrict__ basis,
                                                  float* __restrict__ W) {
    constexpr int per_r = kIn * kMsg;
    int idx = blockIdx.x * blockDim.x + threadIdx.x;
    if (idx >= kR * per_r) return;
    int r = idx / per_r;
    int ic = idx - r * per_r;
    float acc = 0.f;
#pragma unroll
    for (int b = 0; b < kBasis; ++b)
        acc += att[r * kBasis + b] * basis[b * per_r + ic];
    W[idx] = acc;
}

__global__ __launch_bounds__(256) void edge_scatter(
        const float* __restrict__ W,
        const int* __restrict__ gnode,
        const int* __restrict__ snode,
        const int* __restrict__ fidx,
        const float* __restrict__ cj,
        float* __restrict__ h) {
    const int r = blockIdx.y;
    long tid = (long)blockIdx.x * blockDim.x + threadIdx.x;
    const int lane = (int)(tid & 31);
    const long e = tid >> 5;
    if (e >= kE) return;
    const int g = gnode[(long)r * kE + e];
    const int s = snode[(long)r * kE + e];
    const int i0 = fidx[g * 3 + 0];
    const int i1 = fidx[g * 3 + 1];
    const int i2 = fidx[g * 3 + 2];
    const float c = cj[g];
    const float* Wr = W + (size_t)r * kIn * kMsg;
    float* outp = h + (size_t)s * kAgg;
    atomicAdd(&outp[lane],            Wr[(size_t)i0 * kMsg + lane] * c);
    atomicAdd(&outp[kMsg + lane],     Wr[(size_t)i1 * kMsg + lane] * c);
    atomicAdd(&outp[2 * kMsg + lane], Wr[(size_t)i2 * kMsg + lane] * c);
}

__global__ __launch_bounds__(256) void fc_fused(const float* __restrict__ h,
                                                const float* __restrict__ ci,
                                                const float* __restrict__ w_fc,
                                                const float* __restrict__ b_fc,
                                                float* __restrict__ out, int nrows) {
    __shared__ float ws[kAgg * kOut];
    __shared__ float bs[kOut];
    const int lt = threadIdx.y * blockDim.x + threadIdx.x;
    for (int i = lt; i < kAgg * kOut; i += blockDim.x * blockDim.y)
        ws[i] = w_fc[i];
    if (lt < kOut) bs[lt] = b_fc[lt];
    __syncthreads();
    const int row = blockIdx.x * blockDim.y + threadIdx.y;
    if (row >= nrows) return;
    const int col = threadIdx.x;
    const float c = ci[row];
    const float* hr = h + (size_t)row * kAgg;
    float acc = bs[col];
#pragma unroll 8
    for (int k = 0; k < kAgg; ++k) {
        float a = hr[k] * c;
        a = (a >= 0.f) ? a : kSlope * a;
        acc += a * ws[k * kOut + col];
    }
    out[(size_t)row * kOut + col] = acc;
}

extern "C" void kernel_launch(void* const* d_in, const int* in_sizes, int n_in,
                              void* d_out, int out_size, void* d_ws, size_t ws_size,
                              hipStream_t stream) {
    const int*   drug_idx = (const int*)d_in[0];
    const int*   dis_idx  = (const int*)d_in[1];
    const int*   edge_src = (const int*)d_in[2];
    const int*   edge_dst = (const int*)d_in[3];
    const float* cj_drug  = (const float*)d_in[4];
    const float* ci_drug  = (const float*)d_in[5];
    const float* cj_dis   = (const float*)d_in[6];
    const float* ci_dis   = (const float*)d_in[7];
    const float* att      = (const float*)d_in[8];
    const float* basis    = (const float*)d_in[9];
    const float* w_fc     = (const float*)d_in[10];
    const float* b_fc     = (const float*)d_in[11];
    float* out = (float*)d_out;

    auto align256 = [](size_t x) { return (x + 255) & ~(size_t)255; };
    const size_t Wb    = align256((size_t)kR * kIn * kMsg * sizeof(float));     // 512 KB
    const size_t wTb   = align256((size_t)kOut * kAgg * sizeof(float));         // 24 KB
    const size_t bcB   = align256((size_t)kNBuck * sizeof(int));
    const size_t ocB   = align256(sizeof(int));
    const size_t oeB   = align256((size_t)kOvfCap * sizeof(unsigned));          // 16 KB
    const size_t obB   = align256((size_t)kOvfCap * sizeof(int));               // 16 KB
    const size_t binB  = align256((size_t)kNBuck * kSegCap * sizeof(unsigned)); // ~13.87 MB
    const size_t needNew = Wb + wTb + bcB + ocB + oeB + obB + binB;             // ~14.46 MB

    char* p = (char*)d_ws;
    float*    W      = (float*)p;        p += Wb;
    float*    wT     = (float*)p;        p += wTb;
    int*      bcur   = (int*)p;          p += bcB;
    int*      ovfCnt = (int*)p;          p += ocB;
    unsigned* ovfE   = (unsigned*)p;     p += oeB;
    int*      ovfB   = (int*)p;          p += obB;
    unsigned* bin    = (unsigned*)p;

    if (ws_size >= needNew) {
        setup_all<<<dim3(519), 256, 0, stream>>>(att, basis, w_fc, W, wT, bcur, ovfCnt);
        bin_pass<<<dim3(kBinBlocks), 1024, 0, stream>>>(edge_src, edge_dst,
                                                        bcur, bin, ovfCnt, ovfE, ovfB);
        ovf_drain<<<dim3((kOvfCap + 255) / 256), 256, 0, stream>>>(bcur, bin,
                                                                   ovfCnt, ovfE, ovfB);
        gather_fused<<<dim3(kNBuck), 256, 0, stream>>>(bin, bcur, ovfCnt, ovfE, ovfB,
                                                       W, wT, drug_idx, dis_idx,
                                                       cj_drug, cj_dis,
                                                       ci_drug, ci_dis,
                                                       b_fc, out);
    } else {
        // fallback: R1 phased atomic-scatter path (needs ~19.7 MB)
        build_W_fb<<<dim3((kR * kIn * kMsg + 255) / 256), 256, 0, stream>>>(att, basis, W);
        const size_t hB = (size_t)kNDrug * kAgg * sizeof(float);
        float* h = (float*)((char*)d_ws + Wb);
        const int scat_blocks = (int)(((long)kE * 32 + 255) / 256);
        const dim3 scat_grid(scat_blocks, kR);
        hipMemsetAsync(h, 0, hB, stream);
        edge_scatter<<<scat_grid, 256, 0, stream>>>(W, edge_dst, edge_src,
                                                    dis_idx, cj_dis, h);
        fc_fused<<<dim3((kNDrug + 3) / 4), dim3(64, 4), 0, stream>>>(
            h, ci_drug, w_fc, b_fc, out, kNDrug);
        hipMemsetAsync(h, 0, hB, stream);
        edge_scatter<<<scat_grid, 256, 0, stream>>>(W, edge_src, edge_dst,
                                                    drug_idx, cj_drug, h);
        fc_fused<<<dim3((kNDis + 3) / 4), dim3(64, 4), 0, stream>>>(
            h, ci_dis, w_fc, b_fc, out + (size_t)kNDrug * kOut, kNDis);
    }
}

// Round 5
// 526.230 us; speedup vs baseline: 3.2964x; 3.2964x over previous
//
#include <hip/hip_runtime.h>

namespace {
constexpr int kNDrug = 50000;
constexpr int kNDis  = 50000;
constexpr int kE     = 800000;
constexpr int kR     = 2;
constexpr int kIn    = 2048;   // IN_UNITS
constexpr int kMsg   = 32;     // AGG_UNITS / 3
constexpr int kAgg   = 96;     // AGG_UNITS
constexpr int kOut   = 64;     // OUT_UNITS
constexpr int kBasis = 4;
constexpr float kSlope = 0.1f; // LeakyReLU slope
constexpr int kNTot  = kNDis + kNDrug;            // [0,kNDis)=dis nodes, rest drug nodes
constexpr int kBN    = 128;                       // nodes per bucket (pow2 -> shift/mask)
constexpr int kNBuck = (kNTot + kBN - 1) / kBN;   // 782 buckets
constexpr int kSegCap = 4352;                     // entries/bucket (mean 4092, +4sigma), mult of 32
constexpr int kFifoCap = 44;                      // LDS FIFO depth per bucket in bin_pass
constexpr int kBinBlocks = 64;                    // binning blocks (1024 thr each)
constexpr int kOvfCap = 8192;                     // overflow list capacity
constexpr int kNPW   = kBN / 8;                   // nodes per wave in gather (16)
}

// ---------------- one-shot init: W = att@basis, wT = w_fc^T, cursors ----------------
__global__ __launch_bounds__(256) void setup_all(const float* __restrict__ att,
                                                 const float* __restrict__ basis,
                                                 const float* __restrict__ w_fc,
                                                 float* __restrict__ W,
                                                 float* __restrict__ wT,
                                                 int* __restrict__ bcur,
                                                 int* __restrict__ ovfCnt) {
    constexpr int per_r = kIn * kMsg;
    const int blk = blockIdx.x;
    const int t = threadIdx.x;
    if (blk < 512) {                       // W: 2*2048*32 = 131072 elems
        int idx = blk * 256 + t;
        int r = idx / per_r;
        int ic = idx - r * per_r;
        float acc = 0.f;
#pragma unroll
        for (int b = 0; b < kBasis; ++b)
            acc += att[r * kBasis + b] * basis[b * per_r + ic];
        W[idx] = acc;
    } else if (blk == 512) {               // wT[col][k] = w_fc[k][col]
        for (int i = t; i < kOut * kAgg; i += 256) {
            int col = i / kAgg, k = i - col * kAgg;
            wT[i] = w_fc[k * kOut + col];
        }
    } else {                               // blocks 513..516: bcur; 513/t0: ovfCnt
        int i = (blk - 513) * 256 + t;
        if (i < kNBuck) bcur[i] = i * kSegCap;
        if (blk == 513 && t == 0) *ovfCnt = 0;
    }
}

// ---------------- LDS-FIFO binning (64 blocks x 1024 threads) ----------------
// Per-bucket LDS FIFOs; flush in fixed 32-entry (128B) aligned full-line units,
// one global atomic per flush. Rare FIFO overflows go to the ovf list
// (re-inserted by ovf_drain).
// entry = gnode (16b) | rating (bit16) | node-rel-in-bucket (bits 17..23)
__global__ __launch_bounds__(1024) void bin_pass(const int* __restrict__ esrc,
                                                 const int* __restrict__ edst,
                                                 int* __restrict__ bcur,
                                                 unsigned* __restrict__ bin,
                                                 int* __restrict__ ovfCnt,
                                                 unsigned* __restrict__ ovfE,
                                                 int* __restrict__ ovfB) {
    __shared__ unsigned fifo[kNBuck][kFifoCap];  // 137.6 KB
    __shared__ int fcnt[kNBuck];
    __shared__ int flList[kNBuck], flAmt[kNBuck], flPos[kNBuck];
    __shared__ int nFl;

    const int t = threadIdx.x;
    for (int i = t; i < kNBuck; i += 1024) fcnt[i] = 0;

    const int total = kR * kE;
    const int per = (total + kBinBlocks - 1) / kBinBlocks;   // 25000 edges
    const int e0 = blockIdx.x * per;
    const int e1 = (e0 + per < total) ? e0 + per : total;
    __syncthreads();

    auto place = [&](int node, int gn, int r) {
        int bb = node >> 7;
        unsigned ent = (unsigned)gn | ((unsigned)r << 16) | ((unsigned)(node & 127) << 17);
        int pos = atomicAdd(&fcnt[bb], 1);
        if (pos < kFifoCap) {
            fifo[bb][pos] = ent;
        } else {  // statistically never
            int s = atomicAdd(ovfCnt, 1);
            if (s < kOvfCap) { ovfE[s] = ent; ovfB[s] = bb; }
        }
    };

    for (int base = e0; base < e1; base += 1024) {
        int idx = base + t;
        if (idx < e1) {
            int r = (idx >= kE) ? 1 : 0;
            int src = esrc[idx], dst = edst[idx];
            place(dst, src, r);            // dis-side entry
            place(kNDis + src, dst, r);    // drug-side entry
        }
        if (t == 0) nFl = 0;
        __syncthreads();
        // flush-list build: fixed amount 32 per flush
        for (int bb = t; bb < kNBuck; bb += 1024) {
            int c = fcnt[bb]; if (c > kFifoCap) c = kFifoCap;
            if (c >= 32) {
                int slot = atomicAdd(&nFl, 1);
                flList[slot] = bb;
                flPos[slot] = atomicAdd(&bcur[bb], 32);   // stays 32-aligned
            }
        }
        __syncthreads();
        // full-line copies LDS -> bin (one 128B line per flush)
        {
            const int n = nFl;
            const int hw = t >> 5, ln = t & 31;
            for (int it = hw; it < n; it += 32) {
                int bb = flList[it], gp = flPos[it];
                int capEnd = bb * kSegCap + kSegCap;
                unsigned ent = fifo[bb][ln];
                int d = gp + ln;
                if (d < capEnd) bin[d] = ent;
                else { int s = atomicAdd(ovfCnt, 1);
                       if (s < kOvfCap) { ovfE[s] = ent; ovfB[s] = bb; } }
            }
        }
        __syncthreads();
        // compact leftovers (<=12) to FIFO front
        for (int bb = t; bb < kNBuck; bb += 1024) {
            int c = fcnt[bb]; if (c > kFifoCap) c = kFifoCap;
            if (c >= 32) {
                for (int j = 32; j < c; ++j) fifo[bb][j - 32] = fifo[bb][j];
                fcnt[bb] = c - 32;
            } else {
                fcnt[bb] = c;
            }
        }
        __syncthreads();
    }

    // final drain: partial flushes of the <=43-entry tails
    if (t == 0) nFl = 0;
    __syncthreads();
    for (int bb = t; bb < kNBuck; bb += 1024) {
        int c = fcnt[bb]; if (c > kFifoCap) c = kFifoCap;
        if (c) {
            int slot = atomicAdd(&nFl, 1);
            flList[slot] = bb; flAmt[slot] = c;
            flPos[slot] = atomicAdd(&bcur[bb], c);
        }
    }
    __syncthreads();
    const int n = nFl;
    const int hw = t >> 5, ln = t & 31;
    for (int it = hw; it < n; it += 32) {
        int bb = flList[it], f = flAmt[it], gp = flPos[it];
        int capEnd = bb * kSegCap + kSegCap;
        for (int j = ln; j < f; j += 32) {
            unsigned ent = fifo[bb][j];
            int d = gp + j;
            if (d < capEnd) bin[d] = ent;
            else { int s = atomicAdd(ovfCnt, 1);
                   if (s < kOvfCap) { ovfE[s] = ent; ovfB[s] = bb; } }
        }
    }
}

// ---------------- re-insert overflow entries into bin where room remains ----------------
__global__ __launch_bounds__(256) void ovf_drain(int* __restrict__ bcur,
                                                 unsigned* __restrict__ bin,
                                                 const int* __restrict__ ovfCnt,
                                                 const unsigned* __restrict__ ovfE,
                                                 int* __restrict__ ovfB) {
    int n = *ovfCnt; if (n > kOvfCap) n = kOvfCap;
    int i = blockIdx.x * 256 + threadIdx.x;
    if (i >= n) return;
    int bb = ovfB[i];
    int pos = atomicAdd(&bcur[bb], 1);
    if (pos < bb * kSegCap + kSegCap) { bin[pos] = ovfE[i]; ovfB[i] = -1; }
}

// ---------------- fused per-bucket gather + ci/LeakyReLU/FC ----------------
// One 512-thread block per 128-node bucket. LDS = stage(17.4K)+counters+hbuf
// ~= 19.4 KB -> 4 blocks/CU (wave-limited) = 32 waves/CU; all 782 blocks
// co-resident (no tail round). Segment is histogrammed, scanned, scattered
// into per-node LDS lists (sentinel-padded), then each wave runs the proven
// 4-stage software-pipelined register accumulate; FC epilogue goes through a
// per-wave hbuf row (LDS broadcast float4) x wT (L1-hot float4).
__global__ __launch_bounds__(512, 8) void gather_fused(
        const unsigned* __restrict__ bin,
        const int* __restrict__ bcur,
        const int* __restrict__ ovfCnt,
        const unsigned* __restrict__ ovfE,
        const int* __restrict__ ovfB,
        const float* __restrict__ W,
        const float* __restrict__ wT,
        const int* __restrict__ drug_idx, const int* __restrict__ dis_idx,
        const float* __restrict__ cj_drug, const float* __restrict__ cj_dis,
        const float* __restrict__ ci_drug, const float* __restrict__ ci_dis,
        const float* __restrict__ b_fc,
        float* __restrict__ out) {
    __shared__ unsigned stage[kSegCap + 8];    // 17.4 KB (+8 sentinel)
    __shared__ int h[kBN], lb[kBN];
    __shared__ int sbuf[kBN];
    __shared__ float hbuf[8][kAgg];            // 3 KB, one row per wave
    __shared__ int sOvf;

    const int t = threadIdx.x;
    const int b = blockIdx.x;
    if (t < kBN) h[t] = 0;
    if (t == 0) sOvf = (ovfCnt[0] < kOvfCap) ? ovfCnt[0] : kOvfCap;

    const int sb = b * kSegCap;
    __syncthreads();
    int seg = bcur[b] - sb;
    if (seg > kSegCap) seg = kSegCap;

    // histogram rel-node over the segment
    for (int i = t; i < seg; i += 512)
        atomicAdd(&h[bin[sb + i] >> 17], 1);
    __syncthreads();
    // scan of 128 counters
    if (t < kBN) sbuf[t] = h[t];
    __syncthreads();
    for (int o = 1; o < kBN; o <<= 1) {
        int x = 0;
        if (t < kBN && t >= o) x = sbuf[t - o];
        __syncthreads();
        if (t < kBN) sbuf[t] += x;
        __syncthreads();
    }
    if (t < kBN) { int ex = sbuf[t] - h[t]; lb[t] = ex; sbuf[t] = ex; }
    if (t < 8) stage[seg + t] = 0;   // sentinel entries (only ever loaded, never FMA'd)
    __syncthreads();
    // scatter into per-node-ordered LDS staging
    for (int i = t; i < seg; i += 512) {
        unsigned e = bin[sb + i];
        int pos = atomicAdd(&sbuf[e >> 17], 1);
        stage[pos] = e;
    }
    __syncthreads();

    const int wid  = t >> 6;
    const int lane = t & 63;
    const int half = lane >> 5;
    const int fl   = lane & 31;

    const float bias = b_fc[lane];
    const float4* wtp = (const float4*)(wT + lane * kAgg);

    for (int i = 0; i < kNPW; ++i) {
        const int nl = wid * kNPW + i;
        const int g  = b * kBN + nl;
        if (g >= kNTot) break;   // wave-uniform; no block syncs below

        const int* fidxp;
        const float* cjp;
        float civ;
        size_t orow;
        if (g < kNDis) {         // dis dst node: gathers DRUG feats
            fidxp = drug_idx; cjp = cj_drug; civ = ci_dis[g];
            orow = (size_t)(kNDrug + g);
        } else {                 // drug dst node: gathers DIS feats
            fidxp = dis_idx;  cjp = cj_dis;  civ = ci_drug[g - kNDis];
            orow = (size_t)(g - kNDis);
        }

        const int base = lb[nl];
        const int deg  = h[nl];
        float a0 = 0.f, a1 = 0.f, a2 = 0.f;

        // ---- 4-stage software-pipelined accumulate over this half's entries ----
        const unsigned* sp = stage + base + half;
        int n = (deg - half + 1) >> 1;           // entries for this half

        unsigned e0 = sp[0];
        unsigned e1 = sp[2];
        int g0 = (int)(e0 & 0xffffu);
        int i10, i11, i12; float c0, c1;
        {
            int i00 = fidxp[g0 * 3], i01 = fidxp[g0 * 3 + 1], i02 = fidxp[g0 * 3 + 2];
            c0 = cjp[g0];
            unsigned e2p = sp[4];
            int g1 = (int)(e1 & 0xffffu);
            i10 = fidxp[g1 * 3]; i11 = fidxp[g1 * 3 + 1]; i12 = fidxp[g1 * 3 + 2];
            c1 = cjp[g1];
            const float* W0 = W + (((e0 >> 16) & 1u) * (unsigned)(kIn * kMsg));
            float w00 = W0[(i00 << 5) + fl];
            float w01 = W0[(i01 << 5) + fl];
            float w02 = W0[(i02 << 5) + fl];
            unsigned e2 = e2p;
#pragma unroll 2
            for (int tt = 0; tt < n; ++tt) {
                unsigned e3 = sp[2 * tt + 6];                 // prefetch entry tt+3
                int g2 = (int)(e2 & 0xffffu);                 // idx/cj for entry tt+2
                int i20 = fidxp[g2 * 3], i21 = fidxp[g2 * 3 + 1], i22 = fidxp[g2 * 3 + 2];
                float c2 = cjp[g2];
                const float* W1 = W + (((e1 >> 16) & 1u) * (unsigned)(kIn * kMsg));
                float w10 = W1[(i10 << 5) + fl];              // W for entry tt+1
                float w11 = W1[(i11 << 5) + fl];
                float w12 = W1[(i12 << 5) + fl];
                a0 = fmaf(w00, c0, a0);                       // consume entry tt
                a1 = fmaf(w01, c0, a1);
                a2 = fmaf(w02, c0, a2);
                e1 = e2; e2 = e3;
                i10 = i20; i11 = i21; i12 = i22;
                c0 = c1; c1 = c2;
                w00 = w10; w01 = w11; w02 = w12;
            }
        }

        if (sOvf > 0) {          // rare leftover overflow entries
            for (int j = half; j < sOvf; j += 2) {
                int bb = ovfB[j];
                if (bb == b && (int)(ovfE[j] >> 17) == nl) {
                    unsigned e = ovfE[j];
                    int gg = (int)(e & 0xffffu);
                    const float* Wr = W + (((e >> 16) & 1u) * (unsigned)(kIn * kMsg));
                    float c = cjp[gg];
                    a0 = fmaf(Wr[(fidxp[gg * 3]     << 5) + fl], c, a0);
                    a1 = fmaf(Wr[(fidxp[gg * 3 + 1] << 5) + fl], c, a1);
                    a2 = fmaf(Wr[(fidxp[gg * 3 + 2] << 5) + fl], c, a2);
                }
            }
        }

        a0 += __shfl_xor(a0, 32);
        a1 += __shfl_xor(a1, 32);
        a2 += __shfl_xor(a2, 32);

        a0 *= civ; a1 *= civ; a2 *= civ;
        a0 = (a0 >= 0.f) ? a0 : kSlope * a0;
        a1 = (a1 >= 0.f) ? a1 : kSlope * a1;
        a2 = (a2 >= 0.f) ? a2 : kSlope * a2;

        // FC via per-wave hbuf row: same-wave LDS write->read (no barrier needed)
        if (half == 0) {
            hbuf[wid][fl]          = a0;
            hbuf[wid][kMsg + fl]   = a1;
            hbuf[wid][2*kMsg + fl] = a2;
        }
        const float4* hv = (const float4*)(&hbuf[wid][0]);
        float acc = bias;
#pragma unroll 4
        for (int q = 0; q < kAgg / 4; ++q) {
            float4 hq = hv[q];
            float4 wq = wtp[q];
            acc = fmaf(hq.x, wq.x, acc);
            acc = fmaf(hq.y, wq.y, acc);
            acc = fmaf(hq.z, wq.z, acc);
            acc = fmaf(hq.w, wq.w, acc);
        }
        out[orow * kOut + lane] = acc;
    }
}

// ---------------- fallback path (R1 atomic scatter, tiny-ws only) ----------------
__global__ __launch_bounds__(256) void build_W_fb(const float* __restrict__ att,
                                                  const float* __restrict__ basis,
                                                  float* __restrict__ W) {
    constexpr int per_r = kIn * kMsg;
    int idx = blockIdx.x * blockDim.x + threadIdx.x;
    if (idx >= kR * per_r) return;
    int r = idx / per_r;
    int ic = idx - r * per_r;
    float acc = 0.f;
#pragma unroll
    for (int b = 0; b < kBasis; ++b)
        acc += att[r * kBasis + b] * basis[b * per_r + ic];
    W[idx] = acc;
}

__global__ __launch_bounds__(256) void edge_scatter(
        const float* __restrict__ W,
        const int* __restrict__ gnode,
        const int* __restrict__ snode,
        const int* __restrict__ fidx,
        const float* __restrict__ cj,
        float* __restrict__ h) {
    const int r = blockIdx.y;
    long tid = (long)blockIdx.x * blockDim.x + threadIdx.x;
    const int lane = (int)(tid & 31);
    const long e = tid >> 5;
    if (e >= kE) return;
    const int g = gnode[(long)r * kE + e];
    const int s = snode[(long)r * kE + e];
    const int i0 = fidx[g * 3 + 0];
    const int i1 = fidx[g * 3 + 1];
    const int i2 = fidx[g * 3 + 2];
    const float c = cj[g];
    const float* Wr = W + (size_t)r * kIn * kMsg;
    float* outp = h + (size_t)s * kAgg;
    atomicAdd(&outp[lane],            Wr[(size_t)i0 * kMsg + lane] * c);
    atomicAdd(&outp[kMsg + lane],     Wr[(size_t)i1 * kMsg + lane] * c);
    atomicAdd(&outp[2 * kMsg + lane], Wr[(size_t)i2 * kMsg + lane] * c);
}

__global__ __launch_bounds__(256) void fc_fused(const float* __restrict__ h,
                                                const float* __restrict__ ci,
                                                const float* __restrict__ w_fc,
                                                const float* __restrict__ b_fc,
                                                float* __restrict__ out, int nrows) {
    __shared__ float ws[kAgg * kOut];
    __shared__ float bs[kOut];
    const int lt = threadIdx.y * blockDim.x + threadIdx.x;
    for (int i = lt; i < kAgg * kOut; i += blockDim.x * blockDim.y)
        ws[i] = w_fc[i];
    if (lt < kOut) bs[lt] = b_fc[lt];
    __syncthreads();
    const int row = blockIdx.x * blockDim.y + threadIdx.y;
    if (row >= nrows) return;
    const int col = threadIdx.x;
    const float c = ci[row];
    const float* hr = h + (size_t)row * kAgg;
    float acc = bs[col];
#pragma unroll 8
    for (int k = 0; k < kAgg; ++k) {
        float a = hr[k] * c;
        a = (a >= 0.f) ? a : kSlope * a;
        acc += a * ws[k * kOut + col];
    }
    out[(size_t)row * kOut + col] = acc;
}

extern "C" void kernel_launch(void* const* d_in, const int* in_sizes, int n_in,
                              void* d_out, int out_size, void* d_ws, size_t ws_size,
                              hipStream_t stream) {
    const int*   drug_idx = (const int*)d_in[0];
    const int*   dis_idx  = (const int*)d_in[1];
    const int*   edge_src = (const int*)d_in[2];
    const int*   edge_dst = (const int*)d_in[3];
    const float* cj_drug  = (const float*)d_in[4];
    const float* ci_drug  = (const float*)d_in[5];
    const float* cj_dis   = (const float*)d_in[6];
    const float* ci_dis   = (const float*)d_in[7];
    const float* att      = (const float*)d_in[8];
    const float* basis    = (const float*)d_in[9];
    const float* w_fc     = (const float*)d_in[10];
    const float* b_fc     = (const float*)d_in[11];
    float* out = (float*)d_out;

    auto align256 = [](size_t x) { return (x + 255) & ~(size_t)255; };
    const size_t Wb    = align256((size_t)kR * kIn * kMsg * sizeof(float));     // 512 KB
    const size_t wTb   = align256((size_t)kOut * kAgg * sizeof(float));         // 24 KB
    const size_t bcB   = align256((size_t)kNBuck * sizeof(int));
    const size_t ocB   = align256(sizeof(int));
    const size_t oeB   = align256((size_t)kOvfCap * sizeof(unsigned));          // 32 KB
    const size_t obB   = align256((size_t)kOvfCap * sizeof(int));               // 32 KB
    const size_t binB  = align256((size_t)kNBuck * kSegCap * sizeof(unsigned)); // ~13.6 MB
    const size_t needNew = Wb + wTb + bcB + ocB + oeB + obB + binB;             // ~14.25 MB

    char* p = (char*)d_ws;
    float*    W      = (float*)p;        p += Wb;
    float*    wT     = (float*)p;        p += wTb;
    int*      bcur   = (int*)p;          p += bcB;
    int*      ovfCnt = (int*)p;          p += ocB;
    unsigned* ovfE   = (unsigned*)p;     p += oeB;
    int*      ovfB   = (int*)p;          p += obB;
    unsigned* bin    = (unsigned*)p;

    if (ws_size >= needNew) {
        setup_all<<<dim3(517), 256, 0, stream>>>(att, basis, w_fc, W, wT, bcur, ovfCnt);
        bin_pass<<<dim3(kBinBlocks), 1024, 0, stream>>>(edge_src, edge_dst,
                                                        bcur, bin, ovfCnt, ovfE, ovfB);
        ovf_drain<<<dim3((kOvfCap + 255) / 256), 256, 0, stream>>>(bcur, bin,
                                                                   ovfCnt, ovfE, ovfB);
        gather_fused<<<dim3(kNBuck), 512, 0, stream>>>(bin, bcur, ovfCnt, ovfE, ovfB,
                                                       W, wT, drug_idx, dis_idx,
                                                       cj_drug, cj_dis,
                                                       ci_drug, ci_dis,
                                                       b_fc, out);
    } else {
        // fallback: R1 phased atomic-scatter path (needs ~19.7 MB)
        build_W_fb<<<dim3((kR * kIn * kMsg + 255) / 256), 256, 0, stream>>>(att, basis, W);
        const size_t hB = (size_t)kNDrug * kAgg * sizeof(float);
        float* h = (float*)((char*)d_ws + Wb);
        const int scat_blocks = (int)(((long)kE * 32 + 255) / 256);
        const dim3 scat_grid(scat_blocks, kR);
        hipMemsetAsync(h, 0, hB, stream);
        edge_scatter<<<scat_grid, 256, 0, stream>>>(W, edge_dst, edge_src,
                                                    dis_idx, cj_dis, h);
        fc_fused<<<dim3((kNDrug + 3) / 4), dim3(64, 4), 0, stream>>>(
            h, ci_drug, w_fc, b_fc, out, kNDrug);
        hipMemsetAsync(h, 0, hB, stream);
        edge_scatter<<<scat_grid, 256, 0, stream>>>(W, edge_src, edge_dst,
                                                    drug_idx, cj_drug, h);
        fc_fused<<<dim3((kNDis + 3) / 4), dim3(64, 4), 0, stream>>>(
            h, ci_dis, w_fc, b_fc, out + (size_t)kNDrug * kOut, kNDis);
    }
}

// Round 6
// 234.661 us; speedup vs baseline: 7.3922x; 2.2425x over previous
//
#include <hip/hip_runtime.h>

namespace {
constexpr int kNDrug = 50000;
constexpr int kNDis  = 50000;
constexpr int kE     = 800000;
constexpr int kR     = 2;
constexpr int kIn    = 2048;   // IN_UNITS
constexpr int kMsg   = 32;     // AGG_UNITS / 3
constexpr int kAgg   = 96;     // AGG_UNITS
constexpr int kOut   = 64;     // OUT_UNITS
constexpr int kBasis = 4;
constexpr float kSlope = 0.1f; // LeakyReLU slope
constexpr int kNTot  = kNDis + kNDrug;            // [0,kNDis)=dis nodes, rest drug nodes
constexpr int kBN    = 131;                       // nodes per bucket -> 764 blocks <= 768
                                                  // (3-resident x 256 CU) => zero tail round
constexpr int kNBuck = (kNTot + kBN - 1) / kBN;   // 764
constexpr int kSegCap = 4448;                     // entries/bucket (mean 4188, +4sigma), 16-mult
constexpr int kFifoCap = 44;                      // LDS FIFO depth per bucket in bin_pass
constexpr int kBinBlocks = 64;                    // binning blocks (1024 thr each)
constexpr int kOvfCap = 8192;                     // overflow list capacity
constexpr int kNPW   = 17;                        // ceil(kBN/8) nodes per wave in gather
constexpr int kSent  = 16;                        // sentinel pad (covers dual-chain lookahead)
}

// ---------------- one-shot init: W = att@basis, cursors ----------------
__global__ __launch_bounds__(256) void setup_all(const float* __restrict__ att,
                                                 const float* __restrict__ basis,
                                                 float* __restrict__ W,
                                                 int* __restrict__ bcur,
                                                 int* __restrict__ ovfCnt) {
    constexpr int per_r = kIn * kMsg;
    const int blk = blockIdx.x;
    const int t = threadIdx.x;
    if (blk < 512) {                       // W: 2*2048*32 = 131072 elems
        int idx = blk * 256 + t;
        int r = idx / per_r;
        int ic = idx - r * per_r;
        float acc = 0.f;
#pragma unroll
        for (int b = 0; b < kBasis; ++b)
            acc += att[r * kBasis + b] * basis[b * per_r + ic];
        W[idx] = acc;
    } else {                               // blocks 512..515: bcur init; 512/t0: ovfCnt
        int i = (blk - 512) * 256 + t;
        if (i < kNBuck) bcur[i] = i * kSegCap;
        if (blk == 512 && t == 0) *ovfCnt = 0;
    }
}

// ---------------- LDS-FIFO binning (64 blocks x 1024 threads) ----------------
// Per-bucket LDS FIFOs; flush in fixed 32-entry (128B) aligned full-line units,
// one global atomic per flush. Rare FIFO overflows go to the ovf list
// (re-inserted by ovf_drain).
// entry = gnode (16b) | rating (bit16) | node-rel-in-bucket (bits 17..24)
__global__ __launch_bounds__(1024) void bin_pass(const int* __restrict__ esrc,
                                                 const int* __restrict__ edst,
                                                 int* __restrict__ bcur,
                                                 unsigned* __restrict__ bin,
                                                 int* __restrict__ ovfCnt,
                                                 unsigned* __restrict__ ovfE,
                                                 int* __restrict__ ovfB) {
    __shared__ unsigned fifo[kNBuck][kFifoCap];  // 134.5 KB
    __shared__ int fcnt[kNBuck];
    __shared__ int flList[kNBuck], flAmt[kNBuck], flPos[kNBuck];
    __shared__ int nFl;

    const int t = threadIdx.x;
    for (int i = t; i < kNBuck; i += 1024) fcnt[i] = 0;

    const int total = kR * kE;
    const int per = (total + kBinBlocks - 1) / kBinBlocks;   // 25000 edges
    const int e0 = blockIdx.x * per;
    const int e1 = (e0 + per < total) ? e0 + per : total;
    __syncthreads();

    auto place = [&](int node, int gn, int r) {
        int bb = node / kBN;
        int rel = node - bb * kBN;
        unsigned ent = (unsigned)gn | ((unsigned)r << 16) | ((unsigned)rel << 17);
        int pos = atomicAdd(&fcnt[bb], 1);
        if (pos < kFifoCap) {
            fifo[bb][pos] = ent;
        } else {  // statistically never
            int s = atomicAdd(ovfCnt, 1);
            if (s < kOvfCap) { ovfE[s] = ent; ovfB[s] = bb; }
        }
    };

    for (int base = e0; base < e1; base += 1024) {
        int idx = base + t;
        if (idx < e1) {
            int r = (idx >= kE) ? 1 : 0;
            int src = esrc[idx], dst = edst[idx];
            place(dst, src, r);            // dis-side entry
            place(kNDis + src, dst, r);    // drug-side entry
        }
        if (t == 0) nFl = 0;
        __syncthreads();
        // flush-list build: fixed amount 32 per flush
        for (int bb = t; bb < kNBuck; bb += 1024) {
            int c = fcnt[bb]; if (c > kFifoCap) c = kFifoCap;
            if (c >= 32) {
                int slot = atomicAdd(&nFl, 1);
                flList[slot] = bb;
                flPos[slot] = atomicAdd(&bcur[bb], 32);   // stays 32-aligned
            }
        }
        __syncthreads();
        // full-line copies LDS -> bin (one 128B line per flush)
        {
            const int n = nFl;
            const int hw = t >> 5, ln = t & 31;
            for (int it = hw; it < n; it += 32) {
                int bb = flList[it], gp = flPos[it];
                int capEnd = bb * kSegCap + kSegCap;
                unsigned ent = fifo[bb][ln];
                int d = gp + ln;
                if (d < capEnd) bin[d] = ent;
                else { int s = atomicAdd(ovfCnt, 1);
                       if (s < kOvfCap) { ovfE[s] = ent; ovfB[s] = bb; } }
            }
        }
        __syncthreads();
        // compact leftovers (<=12) to FIFO front
        for (int bb = t; bb < kNBuck; bb += 1024) {
            int c = fcnt[bb]; if (c > kFifoCap) c = kFifoCap;
            if (c >= 32) {
                for (int j = 32; j < c; ++j) fifo[bb][j - 32] = fifo[bb][j];
                fcnt[bb] = c - 32;
            } else {
                fcnt[bb] = c;
            }
        }
        __syncthreads();
    }

    // final drain: partial flushes of the <=43-entry tails
    if (t == 0) nFl = 0;
    __syncthreads();
    for (int bb = t; bb < kNBuck; bb += 1024) {
        int c = fcnt[bb]; if (c > kFifoCap) c = kFifoCap;
        if (c) {
            int slot = atomicAdd(&nFl, 1);
            flList[slot] = bb; flAmt[slot] = c;
            flPos[slot] = atomicAdd(&bcur[bb], c);
        }
    }
    __syncthreads();
    const int n = nFl;
    const int hw = t >> 5, ln = t & 31;
    for (int it = hw; it < n; it += 32) {
        int bb = flList[it], f = flAmt[it], gp = flPos[it];
        int capEnd = bb * kSegCap + kSegCap;
        for (int j = ln; j < f; j += 32) {
            unsigned ent = fifo[bb][j];
            int d = gp + j;
            if (d < capEnd) bin[d] = ent;
            else { int s = atomicAdd(ovfCnt, 1);
                   if (s < kOvfCap) { ovfE[s] = ent; ovfB[s] = bb; } }
        }
    }
}

// ---------------- re-insert overflow entries into bin where room remains ----------------
__global__ __launch_bounds__(256) void ovf_drain(int* __restrict__ bcur,
                                                 unsigned* __restrict__ bin,
                                                 const int* __restrict__ ovfCnt,
                                                 const unsigned* __restrict__ ovfE,
                                                 int* __restrict__ ovfB) {
    int n = *ovfCnt; if (n > kOvfCap) n = kOvfCap;
    int i = blockIdx.x * 256 + threadIdx.x;
    if (i >= n) return;
    int bb = ovfB[i];
    int pos = atomicAdd(&bcur[bb], 1);
    if (pos < bb * kSegCap + kSegCap) { bin[pos] = ovfE[i]; ovfB[i] = -1; }
}

// ---- dual-chain 4-stage pipeline pieces (stride 4 in sp-index, offsets 0 / 2) ----
#define ACC_PRO(sp_, OFS_, e1_, e2_, i10_, i11_, i12_, c0_, c1_, w00_, w01_, w02_)      \
  { unsigned e0_ = (sp_)[OFS_]; e1_ = (sp_)[(OFS_) + 4]; e2_ = (sp_)[(OFS_) + 8];       \
    int g0_ = (int)(e0_ & 0xffffu);                                                     \
    int j0_ = fidxp[g0_*3], j1_ = fidxp[g0_*3+1], j2_ = fidxp[g0_*3+2];                 \
    c0_ = cjp[g0_];                                                                     \
    int g1_ = (int)(e1_ & 0xffffu);                                                     \
    i10_ = fidxp[g1_*3]; i11_ = fidxp[g1_*3+1]; i12_ = fidxp[g1_*3+2];                  \
    c1_ = cjp[g1_];                                                                     \
    const float* W0_ = W + (((e0_ >> 16) & 1u) * (unsigned)(kIn * kMsg));               \
    w00_ = W0_[(j0_ << 5) + fl]; w01_ = W0_[(j1_ << 5) + fl]; w02_ = W0_[(j2_ << 5) + fl]; }

#define ACC_BODY(sp_, OFS_, tt_, e1_, e2_, i10_, i11_, i12_, c0_, c1_, w00_, w01_, w02_, a0_, a1_, a2_) \
  { unsigned e3_ = (sp_)[(OFS_) + 4*(tt_) + 12];                                        \
    int g2_ = (int)(e2_ & 0xffffu);                                                     \
    int i20_ = fidxp[g2_*3], i21_ = fidxp[g2_*3+1], i22_ = fidxp[g2_*3+2];              \
    float c2_ = cjp[g2_];                                                               \
    const float* W1_ = W + (((e1_ >> 16) & 1u) * (unsigned)(kIn * kMsg));               \
    float w10_ = W1_[(i10_ << 5) + fl];                                                 \
    float w11_ = W1_[(i11_ << 5) + fl];                                                 \
    float w12_ = W1_[(i12_ << 5) + fl];                                                 \
    a0_ = fmaf(w00_, c0_, a0_); a1_ = fmaf(w01_, c0_, a1_); a2_ = fmaf(w02_, c0_, a2_); \
    e1_ = e2_; e2_ = e3_; i10_ = i20_; i11_ = i21_; i12_ = i22_;                        \
    c0_ = c1_; c1_ = c2_; w00_ = w10_; w01_ = w11_; w02_ = w12_; }

// ---------------- fused per-bucket gather + ci/LeakyReLU/FC ----------------
// One 512-thread block per 131-node bucket; 764 blocks at 3-resident/CU -> all
// co-resident, zero tail round. Segment is histogrammed, scanned, scattered
// into per-node LDS lists (sentinel-padded); each half-wave then runs TWO
// independent interleaved 4-stage software pipelines (~14 loads in flight vs 7)
// and the proven shfl + LDS-ws FC epilogue.
__global__ __launch_bounds__(512, 6) void gather_fused(
        const unsigned* __restrict__ bin,
        const int* __restrict__ bcur,
        const int* __restrict__ ovfCnt,
        const unsigned* __restrict__ ovfE,
        const int* __restrict__ ovfB,
        const float* __restrict__ W,
        const int* __restrict__ drug_idx, const int* __restrict__ dis_idx,
        const float* __restrict__ cj_drug, const float* __restrict__ cj_dis,
        const float* __restrict__ ci_drug, const float* __restrict__ ci_dis,
        const float* __restrict__ w_fc, const float* __restrict__ b_fc,
        float* __restrict__ out) {
    __shared__ float ws[kAgg * kOut];              // 24 KB
    __shared__ float bs[kOut];
    __shared__ unsigned stage[kSegCap + kSent];    // 17.9 KB
    __shared__ int h[kBN], lb[kBN];
    __shared__ int sbuf[kBN];
    __shared__ int sOvf;

    const int t = threadIdx.x;
    const int b = blockIdx.x;
    for (int i = t; i < kAgg * kOut; i += 512) ws[i] = w_fc[i];
    if (t < kOut) bs[t] = b_fc[t];
    if (t < kBN) h[t] = 0;
    if (t == 0) sOvf = (ovfCnt[0] < kOvfCap) ? ovfCnt[0] : kOvfCap;

    const int sb = b * kSegCap;
    __syncthreads();
    int seg = bcur[b] - sb;
    if (seg > kSegCap) seg = kSegCap;

    // histogram rel-node over the segment
    for (int i = t; i < seg; i += 512)
        atomicAdd(&h[bin[sb + i] >> 17], 1);
    __syncthreads();
    // scan of kBN counters (Hillis-Steele; coverage 255 >= 131)
    if (t < kBN) sbuf[t] = h[t];
    __syncthreads();
    for (int o = 1; o < kBN; o <<= 1) {
        int x = 0;
        if (t < kBN && t >= o) x = sbuf[t - o];
        __syncthreads();
        if (t < kBN) sbuf[t] += x;
        __syncthreads();
    }
    if (t < kBN) { int ex = sbuf[t] - h[t]; lb[t] = ex; sbuf[t] = ex; }
    if (t < kSent) stage[seg + t] = 0;   // sentinel entries (loaded, never FMA'd)
    __syncthreads();
    // scatter into per-node-ordered LDS staging
    for (int i = t; i < seg; i += 512) {
        unsigned e = bin[sb + i];
        int pos = atomicAdd(&sbuf[e >> 17], 1);
        stage[pos] = e;
    }
    __syncthreads();

    const int wid  = t >> 6;
    const int lane = t & 63;
    const int half = lane >> 5;
    const int fl   = lane & 31;

    for (int i = 0; i < kNPW; ++i) {
        const int nl = wid * kNPW + i;
        if (nl >= kBN) break;    // wave-uniform
        const int g  = b * kBN + nl;
        if (g >= kNTot) break;   // wave-uniform; no block syncs below

        const int* fidxp;
        const float* cjp;
        float civ;
        size_t orow;
        if (g < kNDis) {         // dis dst node: gathers DRUG feats
            fidxp = drug_idx; cjp = cj_drug; civ = ci_dis[g];
            orow = (size_t)(kNDrug + g);
        } else {                 // drug dst node: gathers DIS feats
            fidxp = dis_idx;  cjp = cj_dis;  civ = ci_drug[g - kNDis];
            orow = (size_t)(g - kNDis);
        }

        const int base = lb[nl];
        const int deg  = h[nl];
        const unsigned* sp = stage + base + half;
        const int n  = (deg - half + 1) >> 1;   // this half's entry count
        const int nA = (n + 1) >> 1;            // chain A: half-entries 0,2,4,..
        const int nB = n >> 1;                  // chain B: half-entries 1,3,5,..

        float a0A = 0.f, a1A = 0.f, a2A = 0.f;
        float a0B = 0.f, a1B = 0.f, a2B = 0.f;
        unsigned eA1, eA2, eB1, eB2;
        int iA0, iA1, iA2, iB0, iB1, iB2;
        float cA0, cA1, cB0, cB1;
        float wA0, wA1, wA2, wB0, wB1, wB2;

        ACC_PRO(sp, 0, eA1, eA2, iA0, iA1, iA2, cA0, cA1, wA0, wA1, wA2);
        ACC_PRO(sp, 2, eB1, eB2, iB0, iB1, iB2, cB0, cB1, wB0, wB1, wB2);

        int tt = 0;
        for (; tt < nB; ++tt) {
            ACC_BODY(sp, 0, tt, eA1, eA2, iA0, iA1, iA2, cA0, cA1, wA0, wA1, wA2,
                     a0A, a1A, a2A);
            ACC_BODY(sp, 2, tt, eB1, eB2, iB0, iB1, iB2, cB0, cB1, wB0, wB1, wB2,
                     a0B, a1B, a2B);
        }
        if (tt < nA) {
            ACC_BODY(sp, 0, tt, eA1, eA2, iA0, iA1, iA2, cA0, cA1, wA0, wA1, wA2,
                     a0A, a1A, a2A);
        }

        float a0 = a0A + a0B, a1 = a1A + a1B, a2 = a2A + a2B;

        if (sOvf > 0) {          // rare leftover overflow entries
            for (int j = half; j < sOvf; j += 2) {
                int bb = ovfB[j];
                if (bb == b && (int)(ovfE[j] >> 17) == nl) {
                    unsigned e = ovfE[j];
                    int gg = (int)(e & 0xffffu);
                    const float* Wr = W + (((e >> 16) & 1u) * (unsigned)(kIn * kMsg));
                    float c = cjp[gg];
                    a0 = fmaf(Wr[(fidxp[gg * 3]     << 5) + fl], c, a0);
                    a1 = fmaf(Wr[(fidxp[gg * 3 + 1] << 5) + fl], c, a1);
                    a2 = fmaf(Wr[(fidxp[gg * 3 + 2] << 5) + fl], c, a2);
                }
            }
        }

        a0 += __shfl_xor(a0, 32);
        a1 += __shfl_xor(a1, 32);
        a2 += __shfl_xor(a2, 32);

        a0 *= civ; a1 *= civ; a2 *= civ;
        a0 = (a0 >= 0.f) ? a0 : kSlope * a0;
        a1 = (a1 >= 0.f) ? a1 : kSlope * a1;
        a2 = (a2 >= 0.f) ? a2 : kSlope * a2;

        float acc = bs[lane];
#pragma unroll
        for (int k = 0; k < 32; ++k)
            acc = fmaf(__shfl(a0, k), ws[k * kOut + lane], acc);
#pragma unroll
        for (int k = 0; k < 32; ++k)
            acc = fmaf(__shfl(a1, k), ws[(32 + k) * kOut + lane], acc);
#pragma unroll
        for (int k = 0; k < 32; ++k)
            acc = fmaf(__shfl(a2, k), ws[(64 + k) * kOut + lane], acc);
        out[orow * kOut + lane] = acc;
    }
}

// ---------------- fallback path (R1 atomic scatter, tiny-ws only) ----------------
__global__ __launch_bounds__(256) void build_W_fb(const float* __restrict__ att,
                                                  const float* __restrict__ basis,
                                                  float* __restrict__ W) {
    constexpr int per_r = kIn * kMsg;
    int idx = blockIdx.x * blockDim.x + threadIdx.x;
    if (idx >= kR * per_r) return;
    int r = idx / per_r;
    int ic = idx - r * per_r;
    float acc = 0.f;
#pragma unroll
    for (int b = 0; b < kBasis; ++b)
        acc += att[r * kBasis + b] * basis[b * per_r + ic];
    W[idx] = acc;
}

__global__ __launch_bounds__(256) void edge_scatter(
        const float* __restrict__ W,
        const int* __restrict__ gnode,
        const int* __restrict__ snode,
        const int* __restrict__ fidx,
        const float* __restrict__ cj,
        float* __restrict__ h) {
    const int r = blockIdx.y;
    long tid = (long)blockIdx.x * blockDim.x + threadIdx.x;
    const int lane = (int)(tid & 31);
    const long e = tid >> 5;
    if (e >= kE) return;
    const int g = gnode[(long)r * kE + e];
    const int s = snode[(long)r * kE + e];
    const int i0 = fidx[g * 3 + 0];
    const int i1 = fidx[g * 3 + 1];
    const int i2 = fidx[g * 3 + 2];
    const float c = cj[g];
    const float* Wr = W + (size_t)r * kIn * kMsg;
    float* outp = h + (size_t)s * kAgg;
    atomicAdd(&outp[lane],            Wr[(size_t)i0 * kMsg + lane] * c);
    atomicAdd(&outp[kMsg + lane],     Wr[(size_t)i1 * kMsg + lane] * c);
    atomicAdd(&outp[2 * kMsg + lane], Wr[(size_t)i2 * kMsg + lane] * c);
}

__global__ __launch_bounds__(256) void fc_fused(const float* __restrict__ h,
                                                const float* __restrict__ ci,
                                                const float* __restrict__ w_fc,
                                                const float* __restrict__ b_fc,
                                                float* __restrict__ out, int nrows) {
    __shared__ float ws[kAgg * kOut];
    __shared__ float bs[kOut];
    const int lt = threadIdx.y * blockDim.x + threadIdx.x;
    for (int i = lt; i < kAgg * kOut; i += blockDim.x * blockDim.y)
        ws[i] = w_fc[i];
    if (lt < kOut) bs[lt] = b_fc[lt];
    __syncthreads();
    const int row = blockIdx.x * blockDim.y + threadIdx.y;
    if (row >= nrows) return;
    const int col = threadIdx.x;
    const float c = ci[row];
    const float* hr = h + (size_t)row * kAgg;
    float acc = bs[col];
#pragma unroll 8
    for (int k = 0; k < kAgg; ++k) {
        float a = hr[k] * c;
        a = (a >= 0.f) ? a : kSlope * a;
        acc += a * ws[k * kOut + col];
    }
    out[(size_t)row * kOut + col] = acc;
}

extern "C" void kernel_launch(void* const* d_in, const int* in_sizes, int n_in,
                              void* d_out, int out_size, void* d_ws, size_t ws_size,
                              hipStream_t stream) {
    const int*   drug_idx = (const int*)d_in[0];
    const int*   dis_idx  = (const int*)d_in[1];
    const int*   edge_src = (const int*)d_in[2];
    const int*   edge_dst = (const int*)d_in[3];
    const float* cj_drug  = (const float*)d_in[4];
    const float* ci_drug  = (const float*)d_in[5];
    const float* cj_dis   = (const float*)d_in[6];
    const float* ci_dis   = (const float*)d_in[7];
    const float* att      = (const float*)d_in[8];
    const float* basis    = (const float*)d_in[9];
    const float* w_fc     = (const float*)d_in[10];
    const float* b_fc     = (const float*)d_in[11];
    float* out = (float*)d_out;

    auto align256 = [](size_t x) { return (x + 255) & ~(size_t)255; };
    const size_t Wb    = align256((size_t)kR * kIn * kMsg * sizeof(float));     // 512 KB
    const size_t bcB   = align256((size_t)kNBuck * sizeof(int));
    const size_t ocB   = align256(sizeof(int));
    const size_t oeB   = align256((size_t)kOvfCap * sizeof(unsigned));          // 32 KB
    const size_t obB   = align256((size_t)kOvfCap * sizeof(int));               // 32 KB
    const size_t binB  = align256((size_t)kNBuck * kSegCap * sizeof(unsigned)); // ~13.0 MB
    const size_t needNew = Wb + bcB + ocB + oeB + obB + binB;                   // ~13.6 MB

    char* p = (char*)d_ws;
    float*    W      = (float*)p;        p += Wb;
    int*      bcur   = (int*)p;          p += bcB;
    int*      ovfCnt = (int*)p;          p += ocB;
    unsigned* ovfE   = (unsigned*)p;     p += oeB;
    int*      ovfB   = (int*)p;          p += obB;
    unsigned* bin    = (unsigned*)p;

    if (ws_size >= needNew) {
        setup_all<<<dim3(516), 256, 0, stream>>>(att, basis, W, bcur, ovfCnt);
        bin_pass<<<dim3(kBinBlocks), 1024, 0, stream>>>(edge_src, edge_dst,
                                                        bcur, bin, ovfCnt, ovfE, ovfB);
        ovf_drain<<<dim3((kOvfCap + 255) / 256), 256, 0, stream>>>(bcur, bin,
                                                                   ovfCnt, ovfE, ovfB);
        gather_fused<<<dim3(kNBuck), 512, 0, stream>>>(bin, bcur, ovfCnt, ovfE, ovfB,
                                                       W, drug_idx, dis_idx,
                                                       cj_drug, cj_dis,
                                                       ci_drug, ci_dis,
                                                       w_fc, b_fc, out);
    } else {
        // fallback: R1 phased atomic-scatter path (needs ~19.7 MB)
        build_W_fb<<<dim3((kR * kIn * kMsg + 255) / 256), 256, 0, stream>>>(att, basis, W);
        const size_t hB = (size_t)kNDrug * kAgg * sizeof(float);
        float* h = (float*)((char*)d_ws + Wb);
        const int scat_blocks = (int)(((long)kE * 32 + 255) / 256);
        const dim3 scat_grid(scat_blocks, kR);
        hipMemsetAsync(h, 0, hB, stream);
        edge_scatter<<<scat_grid, 256, 0, stream>>>(W, edge_dst, edge_src,
                                                    dis_idx, cj_dis, h);
        fc_fused<<<dim3((kNDrug + 3) / 4), dim3(64, 4), 0, stream>>>(
            h, ci_drug, w_fc, b_fc, out, kNDrug);
        hipMemsetAsync(h, 0, hB, stream);
        edge_scatter<<<scat_grid, 256, 0, stream>>>(W, edge_src, edge_dst,
                                                    drug_idx, cj_drug, h);
        fc_fused<<<dim3((kNDis + 3) / 4), dim3(64, 4), 0, stream>>>(
            h, ci_dis, w_fc, b_fc, out + (size_t)kNDrug * kOut, kNDis);
    }
}